// Round 4
// baseline (68.653 us; speedup 1.0000x reference)
//
#include <hip/hip_runtime.h>

// InstanceRouteOptimizationArea — RUDY map via impulse/cumsum trick.
// Round 4: accum occupancy was the limiter (1 block/CU @ 64KB LDS).
//  - NW=8 (16KB LDS: h+v planes), NWIN=32, nchunk=32 -> 1024 blocks =
//    4 blocks/CU, 32 waves/CU. Partials traffic unchanged (grid*tile const).
//  - per-net u32 window mask from bbox: filter = 4B load + bit test.
//  - h/v de-interleaved LDS planes: atomic bank = x mod 32 (all 32 banks).

#define NB 256
#define NW 8          // rows per accumulation window
#define NWIN 32       // NB/NW
#define MAXCHUNK 32

__device__ __forceinline__ long long load_idx(const void* p, long long i, int is64) {
    if (is64) return ((const long long*)p)[i];
    return (long long)((const int*)p)[i];
}

// ---------------- K1: per-net bbox + densities + window mask ----------------
__global__ void bbox_kernel(const float* __restrict__ pin_pos,
                            const float* __restrict__ net_weights,
                            const void* __restrict__ netpin_start,
                            const void* __restrict__ flat_netpin,
                            unsigned* __restrict__ wmask,
                            float2* __restrict__ yb,
                            float4* __restrict__ rd,
                            int num_nets, int num_pins) {
    int gid = blockIdx.x * blockDim.x + threadIdx.x;
    int n = gid >> 2, k = gid & 3;
    if (n >= num_nets) return;
    const int is64 = (((const int*)netpin_start)[1] == 0);
    long long s = load_idx(netpin_start, n, is64);
    long long e = load_idx(netpin_start, n + 1, is64);
    float xmn = 3e38f, xmx = -3e38f, ymn = 3e38f, ymx = -3e38f;
    if (e - s == 4) {
        long long pin = load_idx(flat_netpin, s + k, is64);
        float px = pin_pos[pin], py = pin_pos[pin + num_pins];
        xmn = px; xmx = px; ymn = py; ymx = py;
    } else if (k == 0) {
        for (long long p = s; p < e; ++p) {
            long long pin = load_idx(flat_netpin, p, is64);
            float px = pin_pos[pin], py = pin_pos[pin + num_pins];
            xmn = fminf(xmn, px); xmx = fmaxf(xmx, px);
            ymn = fminf(ymn, py); ymx = fmaxf(ymx, py);
        }
    }
    #pragma unroll
    for (int m = 1; m <= 2; m <<= 1) {
        xmn = fminf(xmn, __shfl_xor(xmn, m));
        xmx = fmaxf(xmx, __shfl_xor(xmx, m));
        ymn = fminf(ymn, __shfl_xor(ymn, m));
        ymx = fmaxf(ymx, __shfl_xor(ymx, m));
    }
    if (k) return;
    if (e <= s) {
        wmask[n] = 0u;
        yb[n] = make_float2(0.f, 0.f);
        rd[n] = make_float4(0.f, 0.f, 0.f, 0.f);
        return;
    }
    float wx = xmx - xmn, wy = ymx - ymn;
    float area = fmaxf(wx * wy, 1e-6f);
    float w = net_weights[n];
    const float INVB = 1.0f / 3.90625f;
    int j0 = (int)floorf(ymn * INVB);
    int j1 = (int)floorf(ymx * INVB);
    unsigned m = 0u;
    if ((unsigned)j0 < 256u)       m |= 1u << (j0 >> 3);
    if ((unsigned)(j0 + 1) < 256u) m |= 1u << ((j0 + 1) >> 3);
    if ((unsigned)j1 < 256u)       m |= 1u << (j1 >> 3);
    if ((unsigned)(j1 + 1) < 256u) m |= 1u << ((j1 + 1) >> 3);
    wmask[n] = m;
    yb[n] = make_float2(ymn, ymx);
    rd[n] = make_float4(xmn, xmx, w * wx / area, w * wy / area);
}

// ---------------- K2: LDS-tile impulse accumulation ----------------
__global__ __launch_bounds__(512) void accum_kernel(
        const unsigned* __restrict__ wmask,
        const float2* __restrict__ yb,
        const float4* __restrict__ rd,
        float* __restrict__ P,
        int num_nets, int nchunk) {
    __shared__ float acc[2 * NW * NB];   // 16 KiB: h plane then v plane
    const int win = blockIdx.x & (NWIN - 1);
    const int chunk = blockIdx.x >> 5;   // NWIN==32
    const int r0 = win * NW;
    const int tid = threadIdx.x;
    const int bs = blockDim.x;
    for (int i = tid; i < 2 * NW * NB; i += bs) acc[i] = 0.f;
    __syncthreads();
    const int c0 = (int)((long long)num_nets * chunk / nchunk);
    const int c1 = (int)((long long)num_nets * (chunk + 1) / nchunk);
    const float BSX = 3.90625f;
    const float INVB = 1.0f / 3.90625f;
    for (int n = c0 + tid; n < c1; n += bs) {
        if (!((wmask[n] >> win) & 1u)) continue;
        float2 y = yb[n];
        float4 r = rd[n];
        float ty0 = y.x * INVB, fj0 = floorf(ty0); int j0 = (int)fj0; float f0 = ty0 - fj0;
        float ty1 = y.y * INVB, fj1 = floorf(ty1); int j1 = (int)fj1; float f1 = ty1 - fj1;
        float tx0 = r.x * INVB, g0 = floorf(tx0); int i0 = (int)g0; float h0 = tx0 - g0;
        float tx1 = r.y * INVB, g1 = floorf(tx1); int i1 = (int)g1; float h1 = tx1 - g1;
        int   jxs[4] = { i0, i0 + 1, i1, i1 + 1 };
        float axs[4] = { BSX * (1.f - h0), BSX * h0, -BSX * (1.f - h1), -BSX * h1 };
        int   rr[4]  = { j0, j0 + 1, j1, j1 + 1 };
        float rw[4]  = { BSX * (1.f - f0), BSX * f0, -BSX * (1.f - f1), -BSX * f1 };
        #pragma unroll
        for (int q = 0; q < 4; ++q) {
            int row = rr[q] - r0;
            if ((unsigned)row >= NW) continue;
            float wh = rw[q] * r.z;
            float wv = rw[q] * r.w;
            float* bh = acc + row * NB;
            float* bv = acc + NW * NB + row * NB;
            #pragma unroll
            for (int p = 0; p < 4; ++p) {
                int x = jxs[p];
                if (x >= NB) continue;
                atomicAdd(bh + x, axs[p] * wh);
                atomicAdd(bv + x, axs[p] * wv);
            }
        }
    }
    __syncthreads();
    // P layout: [chunk][plane][NB rows][NB cols]; block owns rows r0..r0+NW-1.
    for (int i = tid; i < 2 * NW * NB; i += bs) {
        int p = i / (NW * NB);
        int r = (i / NB) % NW;
        int x = i & (NB - 1);
        P[(((long long)chunk * 2 + p) * NB + r0 + r) * NB + x] = acc[i];
    }
}

// ---------------- K3: reduce partials + row cumsum ----------------
__global__ void reduce_scan(const float* __restrict__ P, float* __restrict__ G,
                            int nchunk) {
    int y = blockIdx.x, t = threadIdx.x;
    float h = 0.f, v = 0.f;
    for (int c = 0; c < nchunk; ++c) {
        h += P[(((long long)c * 2 + 0) * NB + y) * NB + t];
        v += P[(((long long)c * 2 + 1) * NB + y) * NB + t];
    }
    __shared__ float sh[NB];
    __shared__ float sv[NB];
    sh[t] = h; sv[t] = v;
    #pragma unroll
    for (int off = 1; off < NB; off <<= 1) {
        __syncthreads();
        float a = (t >= off) ? sh[t - off] : 0.0f;
        float b = (t >= off) ? sv[t - off] : 0.0f;
        __syncthreads();
        sh[t] += a; sv[t] += b;
    }
    __syncthreads();
    G[y * NB + t] = sh[t];                 // h plane
    G[NB * NB + y * NB + t] = sv[t];       // v plane
}

// ---------------- K4: parallel column cumsum + util (transposed store) ----
__global__ void col_scan_util(const float* __restrict__ G, float* __restrict__ utilT) {
    int x = blockIdx.x, t = threadIdx.x;   // t indexes y
    const float INV_CH = 1.0f / (3.90625f * 3.90625f * 1.5625f);
    const float INV_CV = 1.0f / (3.90625f * 3.90625f * 1.45f);
    __shared__ float sh[NB];
    __shared__ float sv[NB];
    sh[t] = G[t * NB + x];
    sv[t] = G[NB * NB + t * NB + x];
    #pragma unroll
    for (int off = 1; off < NB; off <<= 1) {
        __syncthreads();
        float a = (t >= off) ? sh[t - off] : 0.0f;
        float b = (t >= off) ? sv[t - off] : 0.0f;
        __syncthreads();
        sh[t] += a; sv[t] += b;
    }
    __syncthreads();
    float u = fmaxf(sh[t] * INV_CH, sv[t] * INV_CV);
    u = fminf(fmaxf(u, 0.5f), 2.0f);
    utilT[x * NB + t] = u;   // [x][y], coalesced
}

// ---------------- K5: per-instance area (util transposed [x][y]) ----------
__global__ void instance_area(const float* __restrict__ pos,
                              const float* __restrict__ nsx,
                              const float* __restrict__ nsy,
                              const float* __restrict__ utilT,
                              float* __restrict__ out,
                              int num_movable, int num_nodes) {
    int i = blockIdx.x * blockDim.x + threadIdx.x;
    if (i >= num_movable) return;
    const float BSX = 3.90625f;
    const float INVB = 1.0f / 3.90625f;
    float x0f = pos[i];
    float y0f = pos[num_nodes + i];
    float x1f = x0f + nsx[i];
    float y1f = y0f + nsy[i];
    int kx0 = max(0, min(NB - 1, (int)floorf(x0f * INVB)));
    int kx1 = max(0, min(NB - 1, (int)floorf(x1f * INVB)));
    int ky0 = max(0, min(NB - 1, (int)floorf(y0f * INVB)));
    int ky1 = max(0, min(NB - 1, (int)floorf(y1f * INVB)));
    float acc = 0.0f;
    for (int kx = kx0; kx <= kx1; ++kx) {
        float bx = kx * BSX;
        float ovx = fmaxf(fminf(x1f, bx + BSX) - fmaxf(x0f, bx), 0.0f);
        const float* ucol = utilT + kx * NB;
        float accy = 0.0f;
        for (int ky = ky0; ky <= ky1; ++ky) {
            float by = ky * BSX;
            float ovy = fmaxf(fminf(y1f, by + BSX) - fmaxf(y0f, by), 0.0f);
            accy += ovy * ucol[ky];
        }
        acc += accy * ovx;
    }
    out[i] = acc;
}

extern "C" void kernel_launch(void* const* d_in, const int* in_sizes, int n_in,
                              void* d_out, int out_size, void* d_ws, size_t ws_size,
                              hipStream_t stream) {
    const float* pos          = (const float*)d_in[0];
    const float* pin_pos      = (const float*)d_in[1];
    const float* nsx          = (const float*)d_in[2];
    const float* nsy          = (const float*)d_in[3];
    const float* net_weights  = (const float*)d_in[4];
    const void*  netpin_start = d_in[5];
    const void*  flat_netpin  = d_in[6];
    float* out = (float*)d_out;

    int num_pins    = in_sizes[1] / 2;
    int num_nodes   = in_sizes[2];
    int num_nets    = in_sizes[4];
    int num_movable = out_size;

    // Workspace (floats): wmask[n] | yb[2n] | rd[4n] | P[nchunk*2*65536] | G[2*65536] | utilT[65536]
    size_t mk_f   = (size_t)num_nets;           // u32 == 4B
    size_t yb_f   = 2LL * num_nets;
    size_t rd_f   = 4LL * num_nets;
    size_t grid_f = (size_t)NB * NB * 2;
    size_t util_f = (size_t)NB * NB;
    size_t fixed  = mk_f + yb_f + rd_f + grid_f + util_f;
    long long avail = (long long)(ws_size / sizeof(float)) - (long long)fixed;
    int nchunk = (int)(avail / (long long)grid_f);
    if (nchunk < 1) nchunk = 1;
    if (nchunk > MAXCHUNK) nchunk = MAXCHUNK;

    unsigned* wmask = (unsigned*)d_ws;
    float2*   yb  = (float2*)((float*)d_ws + mk_f);
    float4*   rd  = (float4*)((float*)d_ws + mk_f + yb_f);
    float*    P   = (float*)d_ws + mk_f + yb_f + rd_f;
    float*    G   = P + (size_t)nchunk * grid_f;
    float*    ut  = G + grid_f;

    int g1 = (4 * num_nets + 255) / 256;
    bbox_kernel<<<g1, 256, 0, stream>>>(pin_pos, net_weights, netpin_start,
                                        flat_netpin, wmask, yb, rd,
                                        num_nets, num_pins);
    accum_kernel<<<NWIN * nchunk, 512, 0, stream>>>(wmask, yb, rd, P,
                                                    num_nets, nchunk);
    reduce_scan<<<NB, 256, 0, stream>>>(P, G, nchunk);
    col_scan_util<<<NB, 256, 0, stream>>>(G, ut);
    int gi = (num_movable + 255) / 256;
    instance_area<<<gi, 256, 0, stream>>>(pos, nsx, nsy, ut, out,
                                          num_movable, num_nodes);
}